// Round 13
// baseline (110.554 us; speedup 1.0000x reference)
//
#include <hip/hip_runtime.h>
#include <math.h>

#define LSEQ 2048
#define HCH  512
#define NST  64
#define NBATCH 8
#define PIf 3.14159265358979f

// Padded LDS layout: phys(i) = i + i/8 (verified r2)
#define PHYS(i) ((i) + ((i) >> 3))
#define LDSN 2304

__device__ __forceinline__ float2 cmul(float2 a, float2 b) {
    return make_float2(a.x * b.x - a.y * b.y, a.x * b.y + a.y * b.x);
}
__device__ __forceinline__ float2 cadd(float2 a, float2 b) { return make_float2(a.x + b.x, a.y + b.y); }
__device__ __forceinline__ float2 csub(float2 a, float2 b) { return make_float2(a.x - b.x, a.y - b.y); }
__device__ __forceinline__ float2 csq(float2 a) { return make_float2(a.x * a.x - a.y * a.y, 2.f * a.x * a.y); }
template<int INV>
__device__ __forceinline__ float2 rot90(float2 a) {
    return INV ? make_float2(-a.y, a.x) : make_float2(a.y, -a.x);
}

// ---------------------------------------------------------------------------
// In-place FFT machinery, NT=256 (verified r8/r9; conv kernel).
// ---------------------------------------------------------------------------
template<int INV, int STAGE>
__device__ __forceinline__ void radix8_inplace(float2* __restrict__ buf, int tid)
{
    __syncthreads();
    float2 x0 = buf[PHYS(tid)];
    float2 x1 = buf[PHYS(tid + 256)];
    float2 x2 = buf[PHYS(tid + 512)];
    float2 x3 = buf[PHYS(tid + 768)];
    float2 x4 = buf[PHYS(tid + 1024)];
    float2 x5 = buf[PHYS(tid + 1280)];
    float2 x6 = buf[PHYS(tid + 1536)];
    float2 x7 = buf[PHYS(tid + 1792)];
    __syncthreads();

    const int Ns  = 1 << STAGE;
    const int lam = tid & (Ns - 1);
    const int G   = ((tid >> STAGE) << (STAGE + 3)) + lam;
    const float SGN = INV ? 1.f : -1.f;
    float sn, cs;
    __sincosf(SGN * (PIf / (float)(4 * Ns)) * (float)lam, &sn, &cs);
    const float2 T3 = make_float2(cs, sn);
    const float2 T2 = csq(T3);
    const float2 T1 = csq(T2);
    const float r2 = 0.70710678118f;
    const float2 U = cmul(T3, make_float2(r2, SGN * r2));
    float2 t;
    t = cmul(T1, x4); float2 a0 = cadd(x0, t), a4 = csub(x0, t);
    t = cmul(T1, x5); float2 a1 = cadd(x1, t), a5 = csub(x1, t);
    t = cmul(T1, x6); float2 a2 = cadd(x2, t), a6 = csub(x2, t);
    t = cmul(T1, x7); float2 a3 = cadd(x3, t), a7 = csub(x3, t);
    t = cmul(T2, a2);             float2 b0 = cadd(a0, t), b2 = csub(a0, t);
    t = cmul(T2, a3);             float2 b1 = cadd(a1, t), b3 = csub(a1, t);
    t = rot90<INV>(cmul(T2, a6)); float2 b4 = cadd(a4, t), b6 = csub(a4, t);
    t = rot90<INV>(cmul(T2, a7)); float2 b5 = cadd(a5, t), b7 = csub(a5, t);
    t = cmul(T3, b1);             buf[PHYS(G)]          = cadd(b0, t); buf[PHYS(G + 4 * Ns)] = csub(b0, t);
    t = rot90<INV>(cmul(T3, b3)); buf[PHYS(G + 2 * Ns)] = cadd(b2, t); buf[PHYS(G + 6 * Ns)] = csub(b2, t);
    t = cmul(U, b5);              buf[PHYS(G + Ns)]     = cadd(b4, t); buf[PHYS(G + 5 * Ns)] = csub(b4, t);
    t = rot90<INV>(cmul(U, b7));  buf[PHYS(G + 3 * Ns)] = cadd(b6, t); buf[PHYS(G + 7 * Ns)] = csub(b6, t);
}

template<int INV>
__device__ __forceinline__ void radix4_inplace(float2* __restrict__ buf, int tid)
{
    __syncthreads();
    const float SGN = INV ? 1.f : -1.f;
#pragma unroll
    for (int q = 0; q < 2; ++q) {
        const int j = tid + (q << 8);
        float2 A  = buf[PHYS(j)];
        float2 C  = buf[PHYS(j + 512)];
        float2 B  = buf[PHYS(j + 1024)];
        float2 Dd = buf[PHYS(j + 1536)];
        float sn, cs;
        __sincosf(SGN * (PIf / 1024.f) * (float)j, &sn, &cs);
        const float2 v = make_float2(cs, sn);
        const float2 w = csq(v);
        float2 t = cmul(w, B);  float2 m1 = cadd(A, t), m2 = csub(A, t);
        t = cmul(w, Dd);        float2 m3 = cadd(C, t), m4 = csub(C, t);
        const float2 t3 = cmul(v, m3);
        const float2 t4 = rot90<INV>(cmul(v, m4));
        buf[PHYS(j)]        = cadd(m1, t3);
        buf[PHYS(j + 1024)] = csub(m1, t3);
        buf[PHYS(j + 512)]  = cadd(m2, t4);
        buf[PHYS(j + 1536)] = csub(m2, t4);
    }
}

template<int INV>
__device__ __forceinline__ void fft2048_ip(float2* buf, int tid)
{
    radix8_inplace<INV, 0>(buf, tid);
    radix8_inplace<INV, 3>(buf, tid);
    radix8_inplace<INV, 6>(buf, tid);
    radix4_inplace<INV>(buf, tid);
}

// ---------------------------------------------------------------------------
// NEW: in-place FFT machinery, NT=512 (kf kernel). Radix-4 pass fusing
// radix-2 stages (S, S+1), derived by composing the verified r1 radix-2
// Stockham mapping (same derivation path as the verified radix-8):
//   reads  buf[t + m*512]; pairs (x0,x2), (x1,x3) at level 1, twiddle T1
//   G = ((t>>S)<<(S+2)) + lam; T2 = e^{SGN*i*pi*lam/(2Ns)}; T1 = T2^2
//   level 2: (b0,b2) tw T2 -> G, G+2Ns ; (b1,b3) tw rot90(T2) -> G+Ns, G+3Ns
// ---------------------------------------------------------------------------
template<int INV, int STAGE>
__device__ __forceinline__ void radix4_ip512(float2* __restrict__ buf, int tid)
{
    __syncthreads();
    float2 x0 = buf[PHYS(tid)];
    float2 x1 = buf[PHYS(tid + 512)];
    float2 x2 = buf[PHYS(tid + 1024)];
    float2 x3 = buf[PHYS(tid + 1536)];
    __syncthreads();

    const int Ns  = 1 << STAGE;
    const int lam = tid & (Ns - 1);
    const int G   = ((tid >> STAGE) << (STAGE + 2)) + lam;
    const float SGN = INV ? 1.f : -1.f;
    float sn, cs;
    __sincosf(SGN * (PIf / (float)(2 * Ns)) * (float)lam, &sn, &cs);
    const float2 T2 = make_float2(cs, sn);     // e^{SGN*i*pi*lam/(2Ns)}
    const float2 T1 = csq(T2);                 // e^{SGN*i*pi*lam/Ns}
    float2 t;
    t = cmul(T1, x2); float2 b0 = cadd(x0, t), b1 = csub(x0, t);
    t = cmul(T1, x3); float2 b2 = cadd(x1, t), b3 = csub(x1, t);
    const float2 t2 = cmul(T2, b2);
    const float2 t3 = rot90<INV>(cmul(T2, b3));
    buf[PHYS(G)]          = cadd(b0, t2);
    buf[PHYS(G + 2 * Ns)] = csub(b0, t2);
    buf[PHYS(G + Ns)]     = cadd(b1, t3);
    buf[PHYS(G + 3 * Ns)] = csub(b1, t3);
}

// Final radix-2 (stage 10), NT=512: thread t handles j = t, t+512;
// read set == write set per butterfly {j, j+1024} -> entry sync only.
template<int INV>
__device__ __forceinline__ void radix2_ip512(float2* __restrict__ buf, int tid)
{
    __syncthreads();
    const float SGN = INV ? 1.f : -1.f;
#pragma unroll
    for (int q = 0; q < 2; ++q) {
        const int j = tid + (q << 9);
        float2 A = buf[PHYS(j)];
        float2 B = buf[PHYS(j + 1024)];
        float sn, cs;
        __sincosf(SGN * (PIf / 1024.f) * (float)j, &sn, &cs);
        const float2 t = cmul(make_float2(cs, sn), B);
        buf[PHYS(j)]        = cadd(A, t);
        buf[PHYS(j + 1024)] = csub(A, t);
    }
}

template<int INV>
__device__ __forceinline__ void fft2048_ip512(float2* buf, int tid)
{
    radix4_ip512<INV, 0>(buf, tid);
    radix4_ip512<INV, 2>(buf, tid);
    radix4_ip512<INV, 4>(buf, tid);
    radix4_ip512<INV, 6>(buf, tid);
    radix4_ip512<INV, 8>(buf, tid);
    radix2_ip512<INV>(buf, tid);
}

// ---------------------------------------------------------------------------
// Cauchy (VERBATIM r7).
// ---------------------------------------------------------------------------
__global__ __launch_bounds__(256, 4)
void s4_cauchy_kernel(const float* __restrict__ Lr, const float* __restrict__ Li,
                      const float* __restrict__ Pr, const float* __restrict__ Pi,
                      const float* __restrict__ Br, const float* __restrict__ Bi,
                      const float* __restrict__ Cr, const float* __restrict__ Ci,
                      const float* __restrict__ log_dt, float2* __restrict__ at_out)
{
    __shared__ float4 F0[NST];
    __shared__ float4 F1[NST];
    __shared__ float  q1s[NST];

    const int h    = blockIdx.x >> 1;
    const int half = blockIdx.x & 1;
    const int tid  = threadIdx.x;

    if (tid < NST) {
        const float pr = Pr[tid], pi = Pi[tid], br = Br[tid], bi = Bi[tid];
        const float cr = Cr[h * NST + tid], ci = Ci[h * NST + tid];
        F0[tid]  = make_float4(Lr[tid], Li[tid], cr * br + ci * bi, cr * bi - ci * br);
        F1[tid]  = make_float4(cr * pr + ci * pi, cr * pi - ci * pr,
                               pr * br + pi * bi, pr * bi - pi * br);
        q1s[tid] = pr * pr + pi * pi;
    }
    __syncthreads();

    const float dt = expf(log_dt[h]);
    const float a  = 2.0f / dt;

    float tt[4], g[4];
#pragma unroll
    for (int p = 0; p < 4; ++p) {
        const int l = (half << 10) + (p << 8) + tid;
        tt[p] = tanf(PIf * (float)l * (1.0f / 2048.0f));
        g[p]  = a * tt[p];
    }

    float k00r[4], k00i[4], k01r[4], k01i[4];
    float k10r[4], k10i[4], k11r[4], k11i[4];
#pragma unroll
    for (int p = 0; p < 4; ++p) {
        k00r[p] = 0.f; k00i[p] = 0.f; k01r[p] = 0.f; k01i[p] = 0.f;
        k10r[p] = 0.f; k10i[p] = 0.f; k11r[p] = 0.f; k11i[p] = 0.f;
    }

#pragma unroll 2
    for (int n = 0; n < NST; ++n) {
        const float4 f0 = F0[n];
        const float4 f1 = F1[n];
        const float q1 = q1s[n];
        const float x  = -f0.x;
        const float x2 = x * x;
#pragma unroll
        for (int p = 0; p < 4; ++p) {
            const float y   = g[p] - f0.y;
            const float inv = __builtin_amdgcn_rcpf(fmaf(y, y, x2));
            const float rr  = x * inv;
            const float ri  = -y * inv;
            k00r[p] = fmaf(f0.z, rr, fmaf(-f0.w, ri, k00r[p]));
            k00i[p] = fmaf(f0.z, ri, fmaf( f0.w, rr, k00i[p]));
            k01r[p] = fmaf(f1.x, rr, fmaf(-f1.y, ri, k01r[p]));
            k01i[p] = fmaf(f1.x, ri, fmaf( f1.y, rr, k01i[p]));
            k10r[p] = fmaf(f1.z, rr, fmaf(-f1.w, ri, k10r[p]));
            k10i[p] = fmaf(f1.z, ri, fmaf( f1.w, rr, k10i[p]));
            k11r[p] = fmaf(q1, rr, k11r[p]);
            k11i[p] = fmaf(q1, ri, k11i[p]);
        }
    }

    float2* __restrict__ row = at_out + (size_t)h * 2048;
#pragma unroll
    for (int p = 0; p < 4; ++p) {
        const int l = (half << 10) + (p << 8) + tid;
        const float dr = 1.0f + k11r[p], di = k11i[p];
        const float dinv = __builtin_amdgcn_rcpf(fmaf(dr, dr, di * di));
        const float pr_ = k01r[p] * k10r[p] - k01i[p] * k10i[p];
        const float pi_ = k01r[p] * k10i[p] + k01i[p] * k10r[p];
        const float qr = (pr_ * dr + pi_ * di) * dinv;
        const float qi = (pi_ * dr - pr_ * di) * dinv;
        const float sr = k00r[p] - qr, si = k00i[p] - qi;
        row[l] = make_float2(fmaf(-tt[p], si, sr), fmaf(tt[p], sr, si));
    }
}

// ---------------------------------------------------------------------------
// kf kernel — NEW 512-thread in-place version (the single change this round).
// Same math as the r7 kf: K = Re(ifft2048(at))/2048, pack, fft2048, unpack.
// ---------------------------------------------------------------------------
__global__ __launch_bounds__(512, 4)
void s4_kf_kernel(const float2* __restrict__ at_in, float2* __restrict__ Kf)
{
    __shared__ float2 buf[LDSN];

    const int h   = blockIdx.x;
    const int tid = threadIdx.x;   // 0..511
    const float2* __restrict__ at = at_in + (size_t)h * 2048;

#pragma unroll
    for (int q = 0; q < 4; ++q) {
        const int l = tid + (q << 9);
        buf[PHYS(l)] = at[l];
    }

    fft2048_ip512<1>(buf, tid);    // unnormalized inverse; K = .x / 2048

    // pack z[n] = (K[2n] + i K[2n+1]) / 2048, zero tail (read-sync-write)
    __syncthreads();
    float re[2], im[2];
#pragma unroll
    for (int q = 0; q < 2; ++q) {
        const int n = tid + (q << 9);
        re[q] = buf[PHYS(2 * n)].x;
        im[q] = buf[PHYS(2 * n + 1)].x;
    }
    __syncthreads();
    const float sc = 1.0f / 2048.0f;
#pragma unroll
    for (int q = 0; q < 2; ++q) {
        const int n = tid + (q << 9);
        buf[PHYS(n)]        = make_float2(re[q] * sc, im[q] * sc);
        buf[PHYS(n + 1024)] = make_float2(0.f, 0.f);
    }

    fft2048_ip512<0>(buf, tid);    // forward; Z in buf
    __syncthreads();

    // unpack rfft-4096 (verified r2 math; strided for 512 threads)
    float2* __restrict__ out = Kf + (size_t)h * 2049;
    for (int k = tid; k < 1024; k += 512) {
        const float2 Zk = buf[PHYS(k)];
        const float2 Zm = buf[PHYS((2048 - k) & 2047)];
        const float zer = 0.5f * (Zk.x + Zm.x), zei = 0.5f * (Zk.y - Zm.y);
        const float zdr = Zk.x - Zm.x,          zdi = Zk.y + Zm.y;
        const float zor = 0.5f * zdi,           zoi = -0.5f * zdr;
        float s, c;
        __sincosf(-PIf * (float)k * (1.0f / 2048.0f), &s, &c);
        const float txr = c * zor - s * zoi;
        const float txi = c * zoi + s * zor;
        out[k] = make_float2(zer + txr, zei + txi);
        if (k > 0) {
            out[2048 - k] = make_float2(zer - txr, txi - zei);
        } else {
            out[2048] = make_float2(Zk.x - Zk.y, 0.f);
        }
    }
    if (tid == 0) {
        const float2 z = buf[PHYS(1024)];
        out[1024] = make_float2(z.x, -z.y);
    }
}

// ---------------------------------------------------------------------------
// conv kernel (VERBATIM r9/r12 — launch_bounds(256,6); r10/r11 proved higher
// occupancy explodes the strided-IO L3 working set).
// ---------------------------------------------------------------------------
__global__ __launch_bounds__(256, 6)
void s4_conv_kernel(const float* __restrict__ u, float* ws_rows,
                    const float2* __restrict__ Kf, const float* __restrict__ Dv,
                    float* __restrict__ out, int fastpath)
{
    __shared__ float2 buf[LDSN];

    const int bh  = blockIdx.x;
    const int b   = bh >> 9;
    const int h   = bh & 511;
    const int tid = threadIdx.x;

    if (fastpath) {
        const float2* rowv = (const float2*)(ws_rows + (size_t)bh * LSEQ);
        for (int n = tid; n < 1024; n += 256) buf[PHYS(n)] = rowv[n];
    } else {
        const float* ub = u + (size_t)b * LSEQ * HCH + h;
        for (int n = tid; n < 1024; n += 256)
            buf[PHYS(n)] = make_float2(ub[(size_t)(2 * n) * HCH],
                                       ub[(size_t)(2 * n + 1) * HCH]);
    }
    for (int n = 1024 + tid; n < 2048; n += 256) buf[PHYS(n)] = make_float2(0.f, 0.f);

    fft2048_ip<0>(buf, tid);   // Z in buf

    const float2* __restrict__ kf = Kf + (size_t)h * 2049;

    __syncthreads();
    float2 Zk[4], Zm[4], Z1024v;
#pragma unroll
    for (int q = 0; q < 4; ++q) {
        const int k = tid + (q << 8);
        Zk[q] = buf[PHYS(k)];
        Zm[q] = buf[PHYS((2048 - k) & 2047)];
    }
    if (tid == 0) Z1024v = buf[PHYS(1024)];
    __syncthreads();

#pragma unroll
    for (int q = 0; q < 4; ++q) {
        const int k = tid + (q << 8);
        const float2 zk = Zk[q], zm = Zm[q];
        const float zer = 0.5f * (zk.x + zm.x), zei = 0.5f * (zk.y - zm.y);
        const float zdr = zk.x - zm.x,          zdi = zk.y + zm.y;
        const float zor = 0.5f * zdi,           zoi = -0.5f * zdr;
        float s, c;
        __sincosf(-PIf * (float)k * (1.0f / 2048.0f), &s, &c);
        const float txr = c * zor - s * zoi;
        const float txi = c * zoi + s * zor;
        const float2 Xk = make_float2(zer + txr, zei + txi);
        float2 Yk = cmul(Xk, kf[k]);
        float2 Ym;
        if (k > 0) {
            const float2 Xm = make_float2(zer - txr, txi - zei);
            Ym = cmul(Xm, kf[2048 - k]);
        } else {
            const float x2048 = zk.x - zk.y;
            const float2 k2 = kf[2048];
            Ym = make_float2(x2048 * k2.x, x2048 * k2.y);
        }
        const float yer = 0.5f * (Yk.x + Ym.x), yei = 0.5f * (Yk.y - Ym.y);
        const float ydr = Yk.x - Ym.x,          ydi = Yk.y + Ym.y;
        const float yor = 0.5f * (c * ydr + s * ydi);
        const float yoi = 0.5f * (c * ydi - s * ydr);
        buf[PHYS(k)] = make_float2(yer - yoi, yei + yor);
        if (k > 0)
            buf[PHYS(2048 - k)] = make_float2(yer + yoi, yor - yei);
    }
    if (tid == 0) {
        const float2 kk = kf[1024];
        const float2 y = make_float2(Z1024v.x * kk.x + Z1024v.y * kk.y,
                                     Z1024v.x * kk.y - Z1024v.y * kk.x);
        buf[PHYS(1024)] = make_float2(y.x, -y.y);
    }

    fft2048_ip<1>(buf, tid);

    __syncthreads();
    const float Dh = Dv[h];
    const float sc = 1.0f / 2048.0f;
    if (fastpath) {
        float2* rowv = (float2*)(ws_rows + (size_t)bh * LSEQ);
        for (int n = tid; n < 1024; n += 256) {
            const float2 wv = buf[PHYS(n)];
            const float2 xv = rowv[n];
            rowv[n] = make_float2(wv.x * sc + Dh * xv.x,
                                  wv.y * sc + Dh * xv.y);
        }
    } else {
        const float* ub = u + (size_t)b * LSEQ * HCH + h;
        float* ob = out + (size_t)b * LSEQ * HCH + h;
        for (int n = tid; n < 1024; n += 256) {
            const float2 wv = buf[PHYS(n)];
            ob[(size_t)(2 * n) * HCH]     = wv.x * sc + Dh * ub[(size_t)(2 * n) * HCH];
            ob[(size_t)(2 * n + 1) * HCH] = wv.y * sc + Dh * ub[(size_t)(2 * n + 1) * HCH];
        }
    }
}

// ---------------------------------------------------------------------------
// transpose (VERBATIM r7)
// ---------------------------------------------------------------------------
__global__ __launch_bounds__(256)
void transpose_kernel(const float* __restrict__ in, float* __restrict__ out,
                      int rows, int cols)
{
    __shared__ float tile[32][33];
    const int b  = blockIdx.z;
    const int r0 = blockIdx.y << 5;
    const int c0 = blockIdx.x << 5;
    const size_t base = (size_t)b * rows * cols;
    const int tx = threadIdx.x & 31;
    const int ty = threadIdx.x >> 5;
#pragma unroll
    for (int i = 0; i < 32; i += 8)
        tile[ty + i][tx] = in[base + (size_t)(r0 + ty + i) * cols + (c0 + tx)];
    __syncthreads();
#pragma unroll
    for (int i = 0; i < 32; i += 8)
        out[base + (size_t)(c0 + ty + i) * rows + (r0 + tx)] = tile[tx][ty + i];
}

// ---------------------------------------------------------------------------
extern "C" void kernel_launch(void* const* d_in, const int* in_sizes, int n_in,
                              void* d_out, int out_size, void* d_ws, size_t ws_size,
                              hipStream_t stream)
{
    (void)in_sizes; (void)n_in; (void)out_size;
    const float* u  = (const float*)d_in[0];
    const float* Lr = (const float*)d_in[1];
    const float* Li = (const float*)d_in[2];
    const float* Pr = (const float*)d_in[3];
    const float* Pi = (const float*)d_in[4];
    const float* Br = (const float*)d_in[5];
    const float* Bi = (const float*)d_in[6];
    const float* Cr = (const float*)d_in[7];
    const float* Ci = (const float*)d_in[8];
    const float* ld = (const float*)d_in[9];
    const float* Dv = (const float*)d_in[10];
    float* out = (float*)d_out;

    const size_t UT_BYTES = (size_t)NBATCH * HCH * LSEQ * sizeof(float);   // 32 MB
    const size_t KF_BYTES = (size_t)HCH * 2049 * sizeof(float2);           // 8.4 MB
    const int fast = (ws_size >= UT_BYTES + KF_BYTES) ? 1 : 0;

    float*  ut;
    float2* Kf;
    if (fast) { ut = (float*)d_ws; Kf = (float2*)((char*)d_ws + UT_BYTES); }
    else      { ut = (float*)d_ws; Kf = (float2*)d_ws; }

    // at staged in d_out[0, 8MB) — r5-verified placement.
    float2* at = (float2*)d_out;

    hipLaunchKernelGGL(s4_cauchy_kernel, dim3(HCH * 2), dim3(256), 0, stream,
                       Lr, Li, Pr, Pi, Br, Bi, Cr, Ci, ld, at);
    hipLaunchKernelGGL(s4_kf_kernel, dim3(HCH), dim3(512), 0, stream, at, Kf);
    if (fast) {
        hipLaunchKernelGGL(transpose_kernel, dim3(HCH / 32, LSEQ / 32, NBATCH),
                           dim3(256), 0, stream, u, ut, LSEQ, HCH);
    }
    hipLaunchKernelGGL(s4_conv_kernel, dim3(NBATCH * HCH), dim3(256), 0, stream,
                       u, fast ? ut : nullptr, Kf, Dv, out, fast);
    if (fast) {
        hipLaunchKernelGGL(transpose_kernel, dim3(LSEQ / 32, HCH / 32, NBATCH),
                           dim3(256), 0, stream, ut, out, HCH, LSEQ);
    }
}